// Round 1
// baseline (282.728 us; speedup 1.0000x reference)
//
#include <hip/hip_runtime.h>
#include <math.h>

#define L_SEQ 2048
#define E_DIM 2048
#define H_NUM 16
#define D_HEAD 128

typedef __attribute__((ext_vector_type(8))) _Float16 half8;
typedef __attribute__((ext_vector_type(4))) _Float16 half4;
typedef __attribute__((ext_vector_type(4))) float floatx4;

// async global->LDS, 16B per lane. LDS dest is wave-uniform base + lane*16.
static __device__ __forceinline__ void gload16(const void* g, void* lds) {
  __builtin_amdgcn_global_load_lds(
      (const __attribute__((address_space(1))) void*)g,
      (__attribute__((address_space(3))) void*)lds, 16, 0, 0);
}

// ---------------------------------------------------------------------------
// Fused fp32 -> fp16 conversion of x, in_proj_w, out_proj_w (one launch).
// ---------------------------------------------------------------------------
__global__ __launch_bounds__(256)
void cvt3_f32_f16(const float* __restrict__ a, _Float16* __restrict__ oa, int na,
                  const float* __restrict__ b, _Float16* __restrict__ ob, int nb,
                  const float* __restrict__ c, _Float16* __restrict__ oc, int nc) {
  int i = (blockIdx.x * 256 + threadIdx.x) * 8;
  const float* src;
  _Float16* dst;
  if (i < na) {
    src = a + i; dst = oa + i;
  } else if (i < na + nb) {
    src = b + (i - na); dst = ob + (i - na);
  } else if (i < na + nb + nc) {
    src = c + (i - na - nb); dst = oc + (i - na - nb);
  } else {
    return;
  }
  float4 p = *(const float4*)src;
  float4 q = *(const float4*)(src + 4);
  half8 h = {(_Float16)p.x, (_Float16)p.y, (_Float16)p.z, (_Float16)p.w,
             (_Float16)q.x, (_Float16)q.y, (_Float16)q.z, (_Float16)q.w};
  *(half8*)dst = h;
}

// ---------------------------------------------------------------------------
// MFMA GEMM (NT) v2 (R7-verified): unchanged this round.
// ---------------------------------------------------------------------------
template <int TM, int TN, int WR, int WC, int EPI>
__global__ __launch_bounds__(256)
void gemm_mfma(const _Float16* __restrict__ A, const _Float16* __restrict__ B,
               const float* __restrict__ bias, float* __restrict__ C,
               _Float16* __restrict__ qk, _Float16* __restrict__ vt,
               int M, int N, int K) {
  constexpr int RT = TM / (16 * WR);
  constexpr int CT = TN / (16 * WC);
  constexpr int ACH = TM / 8;
  constexpr int NCH = (TM + TN) / 32;

  __shared__ _Float16 As[2][TM * 64];
  __shared__ _Float16 Bs[2][TN * 64];

  const int tid = threadIdx.x;
  const int wave = tid >> 6, lane = tid & 63;
  const int l15 = lane & 15, quad = lane >> 4;
  const int wr = wave / WC, wc = wave % WC;
  const int row0 = blockIdx.y * TM, col0 = blockIdx.x * TN;

  const int srow = lane >> 3;
  const int gc = (lane & 7) ^ srow;

  auto stage = [&](int buf, int k0) {
#pragma unroll
    for (int c = 0; c < NCH; ++c) {
      int chunk = wave * NCH + c;
      if (chunk < ACH) {
        int row = chunk * 8 + srow;
        gload16((const char*)(A + (size_t)(row0 + row) * K + k0) + gc * 16,
                (char*)&As[buf][0] + chunk * 1024);
      } else {
        int bch = chunk - ACH;
        int row = bch * 8 + srow;
        gload16((const char*)(B + (size_t)(col0 + row) * K + k0) + gc * 16,
                (char*)&Bs[buf][0] + bch * 1024);
      }
    }
  };

  floatx4 acc[RT][CT];
#pragma unroll
  for (int i = 0; i < RT; ++i)
#pragma unroll
    for (int j = 0; j < CT; ++j) acc[i][j] = (floatx4){0.f, 0.f, 0.f, 0.f};

  const int niter = K / 64;
  stage(0, 0);

  for (int it = 0; it < niter; ++it) {
    const int cur = it & 1;
    __syncthreads();
    if (it + 1 < niter) stage(cur ^ 1, (it + 1) * 64);

#pragma unroll
    for (int ks = 0; ks < 2; ++ks) {
      half8 af[RT], bf[CT];
#pragma unroll
      for (int t = 0; t < RT; ++t) {
        int r = wr * (16 * RT) + t * 16 + l15;
        af[t] = *(const half8*)&As[cur][r * 64 + (((ks * 4 + quad) ^ (r & 7)) * 8)];
      }
#pragma unroll
      for (int t = 0; t < CT; ++t) {
        int r = wc * (16 * CT) + t * 16 + l15;
        bf[t] = *(const half8*)&Bs[cur][r * 64 + (((ks * 4 + quad) ^ (r & 7)) * 8)];
      }
#pragma unroll
      for (int tr = 0; tr < RT; ++tr)
#pragma unroll
        for (int tc = 0; tc < CT; ++tc)
          acc[tr][tc] = __builtin_amdgcn_mfma_f32_16x16x32_f16(
              af[tr], bf[tc], acc[tr][tc], 0, 0, 0);
    }
  }

  const int crow = row0 + wr * (16 * RT);
  const int ccol = col0 + wc * (16 * CT);

  if (EPI == 0) {
#pragma unroll
    for (int tc = 0; tc < CT; ++tc) {
      int col = ccol + tc * 16 + l15;
      float bb = bias[col];
#pragma unroll
      for (int tr = 0; tr < RT; ++tr)
#pragma unroll
        for (int r = 0; r < 4; ++r)
          C[(size_t)(crow + tr * 16 + quad * 4 + r) * N + col] =
              acc[tr][tc][r] + bb;
    }
  } else if (col0 < 2 * E_DIM) {
#pragma unroll
    for (int tc = 0; tc < CT; ++tc) {
      int col = ccol + tc * 16 + l15;
      float bb = bias[col];
#pragma unroll
      for (int tr = 0; tr < RT; ++tr)
#pragma unroll
        for (int r = 0; r < 4; ++r)
          qk[(size_t)(crow + tr * 16 + quad * 4 + r) * (2 * E_DIM) + col] =
              (_Float16)(acc[tr][tc][r] + bb);
    }
  } else {
#pragma unroll
    for (int tc = 0; tc < CT; ++tc) {
      int col = ccol + tc * 16 + l15;
      float bb = bias[col];
      int vrow = col - 2 * E_DIM;
#pragma unroll
      for (int tr = 0; tr < RT; ++tr) {
        int rbase = crow + tr * 16 + quad * 4;
        half4 h = {(_Float16)(acc[tr][tc][0] + bb), (_Float16)(acc[tr][tc][1] + bb),
                   (_Float16)(acc[tr][tc][2] + bb), (_Float16)(acc[tr][tc][3] + bb)};
        *(half4*)&vt[(size_t)vrow * L_SEQ + rbase] = h;
      }
    }
  }
}

// ---------------------------------------------------------------------------
// MFMA flash attention v6 — LDS-traffic-minimized.
// Grid (H, L/128) = 256 blocks, 512 thr = 8 waves.
// Wave (g = wave>>1, p = wave&1): 32 q-rows (two 16-row MFMA sub-tiles),
// key-tiles of parity p (16 of 32 tiles of 64 keys). Partial (o,l) merged at
// the end (no-max softmax => merge is a plain sum).
//  - K/V quad-buffered in LDS (4 x 16KB each = 128KB), staged via
//    global_load_lds with XOR-pre-swizzled global source (linear LDS dest),
//    read with the same XOR swizzle => bank-uniform, zero ds_writes.
//  - PV uses mfma_f32_16x16x16f16: the S^T fragment layout (k = quad*4+r) IS
//    the x16 A-fragment layout, so P never touches LDS.
// ---------------------------------------------------------------------------
__global__ __launch_bounds__(512, 2)
void attn_mfma(const _Float16* __restrict__ qk, const _Float16* __restrict__ vt,
               const float* __restrict__ bias, _Float16* __restrict__ ctx) {
  const int h = blockIdx.x;
  const int q0 = blockIdx.y * 128;
  const int tid = threadIdx.x;
  const int wave = tid >> 6;
  const int lane = tid & 63;
  const int l15 = lane & 15;
  const int quad = lane >> 4;
  const int g = wave >> 1;  // row-group: rows q0 + g*32 .. +31
  const int p = wave & 1;   // key-tile parity

  // Ks: 4 slots x [64 key][128 d] halfs (16KB), 16B-chunk swizzle c ^= row&7
  // Vst: 4 slots x [128 d][64 key] halfs (16KB), same swizzle
  __shared__ __align__(16) char smem[131072];
  char* const ksmem = smem;
  char* const vsmem = smem + 65536;

  const int qrow = q0 + g * 32;

  // Q fragments (B-operand of S^T = K*Q^T): qa[u][ks]
  half8 qa[2][4];
#pragma unroll
  for (int u = 0; u < 2; ++u) {
    const _Float16* qp =
        qk + (size_t)(qrow + u * 16 + l15) * (2 * E_DIM) + h * D_HEAD + quad * 8;
#pragma unroll
    for (int ks = 0; ks < 4; ++ks) qa[u][ks] = *(const half8*)(qp + ks * 32);
  }

  float l_acc[2] = {0.f, 0.f};
  floatx4 o[2][8];
#pragma unroll
  for (int u = 0; u < 2; ++u)
#pragma unroll
    for (int t = 0; t < 8; ++t) o[u][t] = (floatx4){0.f, 0.f, 0.f, 0.f};

  const float scale = 0.088388347648318447f;  // 1/sqrt(128)

  // stage one key-tile PAIR (128 keys) into slot pair sb,sb+1.
  // 4096 16B-chunks (2x K-tile 1024 + 2x V-tile 1024) over 512 threads.
  auto stage_pair = [&](int kt2, int sb) {
#pragma unroll
    for (int c = 0; c < 8; ++c) {
      int mb = c * 512 + (tid & ~63);  // wave-uniform chunk base
      int m = mb + (tid & 63);
      if (mb < 2048) {  // K region (c = 0..3)
        int sub = mb >> 10;
        int idx = m & 1023, idx0 = mb & 1023;
        int row = idx >> 4, cc = idx & 15;
        gload16(qk + (size_t)(kt2 + sub * 64 + row) * (2 * E_DIM) + E_DIM +
                    h * D_HEAD + ((cc ^ (row & 7)) * 8),
                ksmem + (sb + sub) * 16384 + idx0 * 16);
      } else {  // V region (c = 4..7)
        int mm = mb - 2048;
        int sub = mm >> 10;
        int idx = (m - 2048) & 1023, idx0 = mm & 1023;
        int row = idx >> 3, cc = idx & 7;
        gload16(vt + (size_t)(h * D_HEAD + row) * L_SEQ + kt2 + sub * 64 +
                    ((cc ^ (row & 7)) * 8),
                vsmem + (sb + sub) * 16384 + idx0 * 16);
      }
    }
  };

  stage_pair(0, 0);

#pragma unroll 2
  for (int s = 0; s < 16; ++s) {
    const int kt = s * 128 + p * 64;       // this wave's key-tile base
    const int slot = (s & 1) * 2 + p;
    __syncthreads();  // pair-s staging drained (vmcnt(0) before barrier);
                      // pair-(s+1) slots' readers (superstep s-1) done.

    // bias loads FIRST (so their vmcnt wait leaves stage loads in flight)
    floatx4 bq[2][4];
#pragma unroll
    for (int u = 0; u < 2; ++u)
#pragma unroll
      for (int t4 = 0; t4 < 4; ++t4)
        bq[u][t4] = *(const floatx4*)&bias[(size_t)(qrow + u * 16 + l15) * L_SEQ +
                                           kt + t4 * 16 + quad * 4];

    if (s < 15) stage_pair((s + 1) * 128, ((s + 1) & 1) * 2);

    // ---- S^T = K*Q^T : col=l15=q, row=quad*4+r=key (within 16-block t4) ----
    const char* ksb = ksmem + slot * 16384;
    floatx4 st[2][4];
#pragma unroll
    for (int u = 0; u < 2; ++u)
#pragma unroll
      for (int t4 = 0; t4 < 4; ++t4) st[u][t4] = (floatx4){0.f, 0.f, 0.f, 0.f};
#pragma unroll
    for (int ks = 0; ks < 4; ++ks)
#pragma unroll
      for (int t4 = 0; t4 < 4; ++t4) {
        int row = t4 * 16 + l15;
        half8 kf = *(const half8*)(ksb + row * 256 +
                                   (((4 * ks + quad) ^ (row & 7)) * 16));
        st[0][t4] = __builtin_amdgcn_mfma_f32_16x16x32_f16(kf, qa[0][ks],
                                                           st[0][t4], 0, 0, 0);
        st[1][t4] = __builtin_amdgcn_mfma_f32_16x16x32_f16(kf, qa[1][ks],
                                                           st[1][t4], 0, 0, 0);
      }

    // ---- softmax (no max subtraction); hp = x16 A-fragment directly ----
    half4 hp[2][4];
#pragma unroll
    for (int u = 0; u < 2; ++u) {
      float ls = 0.f;
#pragma unroll
      for (int t4 = 0; t4 < 4; ++t4) {
        float p0 = __expf(fmaf(st[u][t4][0], scale, bq[u][t4][0]));
        float p1 = __expf(fmaf(st[u][t4][1], scale, bq[u][t4][1]));
        float p2 = __expf(fmaf(st[u][t4][2], scale, bq[u][t4][2]));
        float p3 = __expf(fmaf(st[u][t4][3], scale, bq[u][t4][3]));
        ls += (p0 + p1) + (p2 + p3);
        hp[u][t4] = (half4){(_Float16)p0, (_Float16)p1, (_Float16)p2, (_Float16)p3};
      }
      ls += __shfl_xor(ls, 16);
      ls += __shfl_xor(ls, 32);
      l_acc[u] += ls;
    }

    // ---- O += P V via x16 MFMA (P stays in registers) ----
    const char* vsb = vsmem + slot * 16384;
#pragma unroll
    for (int tk = 0; tk < 4; ++tk)
#pragma unroll
      for (int td = 0; td < 8; ++td) {
        int row = td * 16 + l15;
        half4 vf = *(const half4*)(vsb + row * 128 +
                                   (((2 * tk + (quad >> 1)) ^ (row & 7)) * 16) +
                                   (quad & 1) * 8);
        o[0][td] = __builtin_amdgcn_mfma_f32_16x16x16f16(hp[0][tk], vf,
                                                         o[0][td], 0, 0, 0);
        o[1][td] = __builtin_amdgcn_mfma_f32_16x16x16f16(hp[1][tk], vf,
                                                         o[1][td], 0, 0, 0);
      }
  }

  // ---- parity merge (o = o_p0 + o_p1, l = l0 + l1) + epilogue ----
  float* obuf = (float*)smem;            // [4 g][128 col][36] (pad 36: 16B-aligned)
  float* lbuf = (float*)(smem + 73728);  // [4 g][2 u][16]
  __syncthreads();
  if (p == 1) {
#pragma unroll
    for (int u = 0; u < 2; ++u)
#pragma unroll
      for (int t = 0; t < 8; ++t)
        *(floatx4*)&obuf[(size_t)(g * 128 + t * 16 + l15) * 36 + u * 16 + quad * 4] =
            o[u][t];
    if (quad == 0) {
      lbuf[(g * 2 + 0) * 16 + l15] = l_acc[0];
      lbuf[(g * 2 + 1) * 16 + l15] = l_acc[1];
    }
  }
  __syncthreads();
  if (p == 0) {
#pragma unroll
    for (int u = 0; u < 2; ++u) {
      float lt = l_acc[u] + lbuf[(g * 2 + u) * 16 + l15];
      float inv[4];
#pragma unroll
      for (int r = 0; r < 4; ++r) inv[r] = 1.f / __shfl(lt, quad * 4 + r);
#pragma unroll
      for (int t = 0; t < 8; ++t) {
        floatx4 part = *(const floatx4*)&obuf[(size_t)(g * 128 + t * 16 + l15) * 36 +
                                              u * 16 + quad * 4];
#pragma unroll
        for (int r = 0; r < 4; ++r) {
          int rowq = qrow + u * 16 + quad * 4 + r;
          ctx[(size_t)rowq * E_DIM + h * D_HEAD + t * 16 + l15] =
              (_Float16)((o[u][t][r] + part[r]) * inv[r]);
        }
      }
    }
  }
}

// ---------------------------------------------------------------------------
extern "C" void kernel_launch(void* const* d_in, const int* in_sizes, int n_in,
                              void* d_out, int out_size, void* d_ws, size_t ws_size,
                              hipStream_t stream) {
  const float* x          = (const float*)d_in[0];
  const float* bias_mat   = (const float*)d_in[1];
  const float* in_proj_w  = (const float*)d_in[2];
  const float* in_proj_b  = (const float*)d_in[3];
  const float* out_proj_w = (const float*)d_in[4];
  const float* out_proj_b = (const float*)d_in[5];
  float* out = (float*)d_out;

  _Float16* x16 = (_Float16*)d_ws;                         // L*E
  _Float16* w1  = x16 + (size_t)L_SEQ * E_DIM;             // 3E*E
  _Float16* w2  = w1 + (size_t)3 * E_DIM * E_DIM;          // E*E
  _Float16* qk  = w2 + (size_t)E_DIM * E_DIM;              // L*2E
  _Float16* vt  = qk + (size_t)L_SEQ * 2 * E_DIM;          // E*L
  _Float16* ctx = vt + (size_t)E_DIM * L_SEQ;              // L*E

  dim3 blk(256);
  const int nx = L_SEQ * E_DIM, nw1 = 3 * E_DIM * E_DIM, nw2 = E_DIM * E_DIM;

  cvt3_f32_f16<<<(nx + nw1 + nw2) / 2048, blk, 0, stream>>>(
      x, x16, nx, in_proj_w, w1, nw1, out_proj_w, w2, nw2);

  gemm_mfma<128, 128, 2, 2, 1><<<dim3(3 * E_DIM / 128, L_SEQ / 128), blk, 0, stream>>>(
      x16, w1, in_proj_b, nullptr, qk, vt, L_SEQ, 3 * E_DIM, E_DIM);

  attn_mfma<<<dim3(H_NUM, L_SEQ / 128), dim3(512), 0, stream>>>(qk, vt, bias_mat,
                                                                ctx);

  gemm_mfma<128, 64, 4, 1, 0><<<dim3(E_DIM / 64, L_SEQ / 128), blk, 0, stream>>>(
      ctx, w2, out_proj_b, out, nullptr, nullptr, L_SEQ, E_DIM, E_DIM);
}